// Round 4
// baseline (454.966 us; speedup 1.0000x reference)
//
#include <hip/hip_runtime.h>
#include <hip/hip_bf16.h>
#include <math.h>

#define CHUNK 1024

__device__ __forceinline__ unsigned short f2bf(float f) {
    unsigned u = __float_as_uint(f);
    unsigned r = ((u >> 16) & 1u) + 0x7fffu;   // RNE
    return (unsigned short)((u + r) >> 16);
}

// ---------------- GEMM: z = h @ W^T + b -------------------------------------
// 128 nodes x 128 outs per block, 256 threads, 8x8 per thread, K-chunks of 32.
// LDS XOR-swizzle: float4 index = row*8 + (kq ^ ((row>>2)&7)) -> conflict-free
// staging writes AND fragment reads (slots spread over all 8 bank groups).
__global__ __launch_bounds__(256) void k_gemm(const float* __restrict__ h,
                                              const float* __restrict__ W,
                                              const float* __restrict__ bias,
                                              float* __restrict__ z, int N) {
    __shared__ float4 hs4[1024];   // 128 rows x 8 float4 (32 k-floats), 16 KB
    __shared__ float4 ws4[1024];   // 128 outs x 8 float4, 16 KB
    const int t = threadIdx.x;
    const int tx = t & 15, ty = t >> 4;
    const int n0 = blockIdx.x * 128;
    const int swH = ty & 7, swW = tx & 7;

    float acc[8][8];
#pragma unroll
    for (int i = 0; i < 8; ++i)
#pragma unroll
        for (int j = 0; j < 8; ++j) acc[i][j] = 0.f;

    float4 hreg[4], wreg[4];
#pragma unroll
    for (int q = 0; q < 4; ++q) {
        int idx = q * 256 + t;
        int r = idx >> 3, kq = idx & 7;
        int hn = n0 + r; if (hn > N - 1) hn = N - 1;
        hreg[q] = *reinterpret_cast<const float4*>(&h[(size_t)hn * 128 + kq * 4]);
        wreg[q] = *reinterpret_cast<const float4*>(&W[(size_t)r * 128 + kq * 4]);
    }

    for (int kc = 0; kc < 4; ++kc) {
#pragma unroll
        for (int q = 0; q < 4; ++q) {
            int idx = q * 256 + t;
            int r = idx >> 3, kq = idx & 7;
            int a4 = r * 8 + (kq ^ ((r >> 2) & 7));
            hs4[a4] = hreg[q];
            ws4[a4] = wreg[q];
        }
        __syncthreads();
        if (kc < 3) {   // prefetch next chunk into regs; latency hides under MFAs
#pragma unroll
            for (int q = 0; q < 4; ++q) {
                int idx = q * 256 + t;
                int r = idx >> 3, kq = idx & 7;
                int koff = (kc + 1) * 32 + kq * 4;
                int hn = n0 + r; if (hn > N - 1) hn = N - 1;
                hreg[q] = *reinterpret_cast<const float4*>(&h[(size_t)hn * 128 + koff]);
                wreg[q] = *reinterpret_cast<const float4*>(&W[(size_t)r * 128 + koff]);
            }
        }
#pragma unroll
        for (int kq = 0; kq < 8; ++kq) {
            float4 hf[8];
#pragma unroll
            for (int b = 0; b < 2; ++b)
#pragma unroll
                for (int s = 0; s < 4; ++s)
                    hf[b * 4 + s] = hs4[(4 * ty + s + 64 * b) * 8 + (kq ^ swH)];
#pragma unroll
            for (int bo = 0; bo < 2; ++bo)
#pragma unroll
                for (int r = 0; r < 4; ++r) {
                    float4 wf = ws4[(4 * tx + r + 64 * bo) * 8 + (kq ^ swW)];
                    int oi = bo * 4 + r;
#pragma unroll
                    for (int ni = 0; ni < 8; ++ni)
                        acc[ni][oi] += hf[ni].x * wf.x + hf[ni].y * wf.y
                                     + hf[ni].z * wf.z + hf[ni].w * wf.w;
                }
        }
        __syncthreads();
    }

    float4 bq0 = *reinterpret_cast<const float4*>(&bias[4 * tx]);
    float4 bq1 = *reinterpret_cast<const float4*>(&bias[64 + 4 * tx]);
#pragma unroll
    for (int ni = 0; ni < 8; ++ni) {
        int node = n0 + 4 * ty + (ni & 3) + 64 * (ni >> 2);
        if (node < N) {
            float4 v0 = make_float4(acc[ni][0] + bq0.x, acc[ni][1] + bq0.y,
                                    acc[ni][2] + bq0.z, acc[ni][3] + bq0.w);
            float4 v1 = make_float4(acc[ni][4] + bq1.x, acc[ni][5] + bq1.y,
                                    acc[ni][6] + bq1.z, acc[ni][7] + bq1.w);
            *reinterpret_cast<float4*>(&z[(size_t)node * 128 + 4 * tx]) = v0;
            *reinterpret_cast<float4*>(&z[(size_t)node * 128 + 64 + 4 * tx]) = v1;
        }
    }
}

// ------------- per-node score halves + bf16 z copy (z is L2-hot here) -------
__global__ __launch_bounds__(256) void k_scores(const float* __restrict__ z,
                                                const float* __restrict__ att,
                                                float* __restrict__ s_src,
                                                float* __restrict__ s_dst,
                                                unsigned int* __restrict__ zb, int N) {
    int gid = blockIdx.x * 256 + threadIdx.x;
    if (gid >= N * 4) return;
    int n = gid >> 2, hd = gid & 3;
    const float* zp = z + (size_t)n * 128 + hd * 32;
    const float* as = att + hd * 65;
    float ss = 0.f, sd = 0.f;
    unsigned pk[16];
#pragma unroll
    for (int i = 0; i < 32; i += 4) {
        float4 v = *reinterpret_cast<const float4*>(zp + i);
        ss += v.x * as[i] + v.y * as[i + 1] + v.z * as[i + 2] + v.w * as[i + 3];
        sd += v.x * as[32 + i] + v.y * as[32 + i + 1] + v.z * as[32 + i + 2] + v.w * as[32 + i + 3];
        pk[i / 2]     = ((unsigned)f2bf(v.y) << 16) | f2bf(v.x);
        pk[i / 2 + 1] = ((unsigned)f2bf(v.w) << 16) | f2bf(v.z);
    }
    s_src[gid] = ss;
    s_dst[gid] = sd;
    uint4* d4 = reinterpret_cast<uint4*>(zb + (size_t)n * 64 + hd * 16);
    d4[0] = make_uint4(pk[0], pk[1], pk[2], pk[3]);
    d4[1] = make_uint4(pk[4], pk[5], pk[6], pk[7]);
    d4[2] = make_uint4(pk[8], pk[9], pk[10], pk[11]);
    d4[3] = make_uint4(pk[12], pk[13], pk[14], pk[15]);
}

// ------------- CSR build: histogram -----------------------------------------
__global__ __launch_bounds__(256) void k_hist(const int* __restrict__ dst,
                                              int* __restrict__ counts, int E) {
    int e = blockIdx.x * 256 + threadIdx.x;
    if (e < E) atomicAdd(&counts[dst[e]], 1);
}

__global__ __launch_bounds__(256) void k_scan_block(const int* __restrict__ counts,
                                                    int* __restrict__ offs,
                                                    int* __restrict__ bsum, int N) {
    __shared__ int sd[256];
    int t = threadIdx.x, b = blockIdx.x;
    int i0 = b * CHUNK + t * 4;
    int c[4];
#pragma unroll
    for (int j = 0; j < 4; ++j) c[j] = (i0 + j < N) ? counts[i0 + j] : 0;
    int tsum = c[0] + c[1] + c[2] + c[3];
    sd[t] = tsum;
    __syncthreads();
    for (int d = 1; d < 256; d <<= 1) {
        int v = (t >= d) ? sd[t - d] : 0;
        __syncthreads();
        sd[t] += v;
        __syncthreads();
    }
    int pre = sd[t] - tsum;
#pragma unroll
    for (int j = 0; j < 4; ++j) {
        if (i0 + j < N) offs[i0 + j] = pre;
        pre += c[j];
    }
    if (t == 255) bsum[b] = sd[255];
}

__global__ void k_scan_top(const int* __restrict__ bsum, int* __restrict__ bscan, int nb) {
    int lane = threadIdx.x & 63;
    int x = (lane < nb) ? bsum[lane] : 0;
    int own = x;
    for (int d = 1; d < 64; d <<= 1) {
        int v = __shfl_up(x, d);
        if (lane >= d) x += v;
    }
    if (lane < nb) bscan[lane] = x - own;
}

__global__ __launch_bounds__(256) void k_addoff(int* __restrict__ offs,
                                                int* __restrict__ cursor,
                                                const int* __restrict__ bscan, int N) {
    int i = blockIdx.x * 256 + threadIdx.x;
    if (i < N) {
        int o = offs[i] + bscan[i >> 10];
        offs[i] = o;
        cursor[i] = o;
    }
}

// ------------- scatter: bucket by dst, compute alpha ONCE per edge ----------
__global__ __launch_bounds__(256) void k_scatter(const int* __restrict__ src,
                                                 const int* __restrict__ dst,
                                                 const float* __restrict__ ef,
                                                 const float* __restrict__ att,
                                                 const float* __restrict__ s_src,
                                                 const float* __restrict__ s_dst,
                                                 int* __restrict__ cursor,
                                                 int* __restrict__ s_sorted,
                                                 uint2* __restrict__ alpha2, int E) {
    int e = blockIdx.x * 256 + threadIdx.x;
    if (e >= E) return;
    int s = src[e], d = dst[e];
    float f = ef[e];
    int pos = atomicAdd(&cursor[d], 1);
    float4 ss = *reinterpret_cast<const float4*>(&s_src[(size_t)s * 4]);
    float4 sd = *reinterpret_cast<const float4*>(&s_dst[(size_t)d * 4]);
    const float* ssp = (const float*)&ss;
    const float* sdp = (const float*)&sd;
    float a[4];
#pragma unroll
    for (int hd = 0; hd < 4; ++hd) {
        float sc = ssp[hd] + sdp[hd] + f * att[hd * 65 + 64];
        sc = sc >= 0.f ? sc : 0.2f * sc;
        sc = fminf(fmaxf(sc, -20.f), 20.f);
        a[hd] = expf(sc);
    }
    s_sorted[pos] = s;
    alpha2[pos] = make_uint2(((unsigned)f2bf(a[1]) << 16) | f2bf(a[0]),
                             ((unsigned)f2bf(a[3]) << 16) | f2bf(a[2]));
}

// ------------- fused: aggregate (bf16 z) + residual + LN + ELU --------------
// one 64-lane wave per node; lane owns channels [2*lane, 2*lane+1]
__global__ __launch_bounds__(256) void k_agg_final(const int* __restrict__ offs,
                                                   const int* __restrict__ counts,
                                                   const int* __restrict__ s_sorted,
                                                   const uint2* __restrict__ alpha2,
                                                   const unsigned int* __restrict__ zb,
                                                   const float* __restrict__ z,
                                                   const float* __restrict__ g,
                                                   const float* __restrict__ bparm,
                                                   float* __restrict__ out, int N) {
    int wave = threadIdx.x >> 6, lane = threadIdx.x & 63;
    int n = blockIdx.x * 4 + wave;
    if (n >= N) return;
    const int start = offs[n], len = counts[n];
    const int hd = lane >> 4;
    const int c = lane * 2;
    float ax = 0.f, ay = 0.f, da = 0.f;
    float bx = 0.f, by = 0.f, db = 0.f;
    int i = start;
    const int end = start + len;
    for (; i + 1 < end; i += 2) {
        int s0 = s_sorted[i], s1 = s_sorted[i + 1];
        uint2 al0 = alpha2[i], al1 = alpha2[i + 1];
        unsigned p0 = zb[(size_t)s0 * 64 + lane];
        unsigned p1 = zb[(size_t)s1 * 64 + lane];
        unsigned u0 = (hd & 2) ? al0.y : al0.x;
        unsigned u1 = (hd & 2) ? al1.y : al1.x;
        float a0 = __uint_as_float((hd & 1) ? (u0 & 0xffff0000u) : (u0 << 16));
        float a1 = __uint_as_float((hd & 1) ? (u1 & 0xffff0000u) : (u1 << 16));
        float x00 = __uint_as_float(p0 << 16), x01 = __uint_as_float(p0 & 0xffff0000u);
        float x10 = __uint_as_float(p1 << 16), x11 = __uint_as_float(p1 & 0xffff0000u);
        ax += x00 * a0; ay += x01 * a0; da += a0;
        bx += x10 * a1; by += x11 * a1; db += a1;
    }
    if (i < end) {
        int s0 = s_sorted[i];
        uint2 al0 = alpha2[i];
        unsigned p0 = zb[(size_t)s0 * 64 + lane];
        unsigned u0 = (hd & 2) ? al0.y : al0.x;
        float a0 = __uint_as_float((hd & 1) ? (u0 & 0xffff0000u) : (u0 << 16));
        ax += __uint_as_float(p0 << 16) * a0;
        ay += __uint_as_float(p0 & 0xffff0000u) * a0;
        da += a0;
    }

    float inv = 1.f / (da + db + 1e-6f);
    float2 zv = *reinterpret_cast<const float2*>(&z[(size_t)n * 128 + c]);
    float x0 = (ax + bx) * inv + zv.x;
    float x1 = (ay + by) * inv + zv.y;
    float s = x0 + x1;
    for (int off = 32; off; off >>= 1) s += __shfl_xor(s, off);
    float mu = s * (1.f / 128.f);
    float d0 = x0 - mu, d1 = x1 - mu;
    float q = d0 * d0 + d1 * d1;
    for (int off = 32; off; off >>= 1) q += __shfl_xor(q, off);
    float rstd = rsqrtf(q * (1.f / 128.f) + 1e-5f);
    float2 gg = *reinterpret_cast<const float2*>(&g[c]);
    float2 bb = *reinterpret_cast<const float2*>(&bparm[c]);
    float y0 = d0 * rstd * gg.x + bb.x;
    float y1 = d1 * rstd * gg.y + bb.y;
    y0 = y0 > 0.f ? y0 : expf(y0) - 1.f;
    y1 = y1 > 0.f ? y1 : expf(y1) - 1.f;
    *reinterpret_cast<float2*>(&out[(size_t)n * 128 + c]) = make_float2(y0, y1);
}

extern "C" void kernel_launch(void* const* d_in, const int* in_sizes, int n_in,
                              void* d_out, int out_size, void* d_ws, size_t ws_size,
                              hipStream_t stream) {
    const float* h   = (const float*)d_in[0];
    const int*   ei  = (const int*)d_in[1];
    const float* ef  = (const float*)d_in[2];
    const float* Ww  = (const float*)d_in[3];
    const float* Wb  = (const float*)d_in[4];
    const float* att = (const float*)d_in[5];
    const float* lng = (const float*)d_in[6];
    const float* lnb = (const float*)d_in[7];
    float* out = (float*)d_out;

    const int N = in_sizes[0] / 128;   // 50000
    const int E = in_sizes[1] / 2;     // 800000
    const int* src = ei;
    const int* dst = ei + E;
    const int nb = (N + CHUNK - 1) / CHUNK;   // 49 (<=64 required)

    char* ws = (char*)d_ws;
    float*        z        = (float*)ws;        ws += (size_t)N * 128 * 4;
    unsigned int* zb       = (unsigned int*)ws; ws += (size_t)N * 64 * 4;
    float*        s_src    = (float*)ws;        ws += (size_t)N * 4 * 4;
    float*        s_dst    = (float*)ws;        ws += (size_t)N * 4 * 4;
    int*          counts   = (int*)ws;          ws += (size_t)N * 4;
    int*          offs     = (int*)ws;          ws += (size_t)N * 4;
    int*          cursor   = (int*)ws;          ws += (size_t)N * 4;
    int*          bsum     = (int*)ws;          ws += (size_t)64 * 4;
    int*          bscan    = (int*)ws;          ws += (size_t)64 * 4;
    int*          s_sorted = (int*)ws;          ws += (size_t)E * 4;
    uint2*        alpha2   = (uint2*)ws;        ws += (size_t)E * 8;

    hipMemsetAsync(counts, 0, (size_t)N * 4, stream);

    k_gemm<<<(N + 127) / 128, 256, 0, stream>>>(h, Ww, Wb, z, N);
    k_hist<<<(E + 255) / 256, 256, 0, stream>>>(dst, counts, E);
    k_scores<<<(N * 4 + 255) / 256, 256, 0, stream>>>(z, att, s_src, s_dst, zb, N);
    k_scan_block<<<nb, 256, 0, stream>>>(counts, offs, bsum, N);
    k_scan_top<<<1, 64, 0, stream>>>(bsum, bscan, nb);
    k_addoff<<<(N + 255) / 256, 256, 0, stream>>>(offs, cursor, bscan, N);
    k_scatter<<<(E + 255) / 256, 256, 0, stream>>>(src, dst, ef, att, s_src, s_dst, cursor, s_sorted, alpha2, E);
    k_agg_final<<<(N + 3) / 4, 256, 0, stream>>>(offs, counts, s_sorted, alpha2, zb, z, lng, lnb, out, N);
}

// Round 5
// 201.473 us; speedup vs baseline: 2.2582x; 2.2582x over previous
//
#include <hip/hip_runtime.h>
#include <hip/hip_bf16.h>
#include <math.h>

#define CHUNK 1024

__device__ __forceinline__ unsigned short f2bf(float f) {
    unsigned u = __float_as_uint(f);
    unsigned r = ((u >> 16) & 1u) + 0x7fffu;   // RNE
    return (unsigned short)((u + r) >> 16);
}

// ---------------- GEMM: z = h @ W^T + b -------------------------------------
// 64 nodes x 64 outs per block (grid.y picks out-half), 256 threads, 4x4/thread.
// Wt k-major with column-group XOR swizzle: group' = (ol>>2) ^ ((k>>2)&15).
// Staging scalar writes: 2-way conflict; compute float4 reads: 2-way. (Round-3
// layout had 32-way on staging writes = +40us; round-4 8x8 tile spilled regs.)
__global__ __launch_bounds__(256) void k_gemm(const float* __restrict__ h,
                                              const float* __restrict__ W,
                                              const float* __restrict__ bias,
                                              float* __restrict__ z, int N) {
    __shared__ float Wt[128 * 64];   // 32 KB, swizzled k-major
    __shared__ float hl[64][132];    // 33.8 KB, padded row-major
    const int t = threadIdx.x;
    const int obase = blockIdx.y * 64;
    const int n0 = blockIdx.x * 64;

    // stage W: 64 rows x 128 k = 2048 float4 loads, 4 scalar LDS writes each
    for (int i = 0; i < 8; ++i) {
        int f = i * 256 + t;
        int ol = f >> 5;            // out row 0..63
        int m = f & 31;             // k-group 0..31 (k4 = 4m)
        float4 w = *reinterpret_cast<const float4*>(&W[(size_t)(obase + ol) * 128 + m * 4]);
        int swzcol = (((ol >> 2) ^ (m & 15)) << 2) | (ol & 3);
        Wt[(4 * m + 0) * 64 + swzcol] = w.x;
        Wt[(4 * m + 1) * 64 + swzcol] = w.y;
        Wt[(4 * m + 2) * 64 + swzcol] = w.z;
        Wt[(4 * m + 3) * 64 + swzcol] = w.w;
    }
    // stage h: 64 rows x 128 = 2048 float4
    for (int i = 0; i < 8; ++i) {
        int f = i * 256 + t;
        int r = f >> 5, k4 = (f & 31) * 4;
        int hn = n0 + r; if (hn > N - 1) hn = N - 1;
        *reinterpret_cast<float4*>(&hl[r][k4]) =
            *reinterpret_cast<const float4*>(&h[(size_t)hn * 128 + k4]);
    }
    __syncthreads();

    const int og = t & 15;          // out group: outs og*4..og*4+3
    const int wg = t >> 4;          // node group: nodes wg*4..wg*4+3
    float acc[4][4];
#pragma unroll
    for (int s = 0; s < 4; ++s)
#pragma unroll
        for (int j = 0; j < 4; ++j) acc[s][j] = 0.f;

#pragma unroll 4
    for (int k = 0; k < 128; ++k) {
        int g = (k >> 2) & 15;
        float4 wf = *reinterpret_cast<const float4*>(&Wt[k * 64 + ((og ^ g) << 2)]);
        float h0 = hl[wg * 4 + 0][k];
        float h1 = hl[wg * 4 + 1][k];
        float h2 = hl[wg * 4 + 2][k];
        float h3 = hl[wg * 4 + 3][k];
        acc[0][0] += h0 * wf.x; acc[0][1] += h0 * wf.y; acc[0][2] += h0 * wf.z; acc[0][3] += h0 * wf.w;
        acc[1][0] += h1 * wf.x; acc[1][1] += h1 * wf.y; acc[1][2] += h1 * wf.z; acc[1][3] += h1 * wf.w;
        acc[2][0] += h2 * wf.x; acc[2][1] += h2 * wf.y; acc[2][2] += h2 * wf.z; acc[2][3] += h2 * wf.w;
        acc[3][0] += h3 * wf.x; acc[3][1] += h3 * wf.y; acc[3][2] += h3 * wf.z; acc[3][3] += h3 * wf.w;
    }

    float4 bq = *reinterpret_cast<const float4*>(&bias[obase + og * 4]);
#pragma unroll
    for (int s = 0; s < 4; ++s) {
        int node = n0 + wg * 4 + s;
        if (node < N) {
            float4 v = make_float4(acc[s][0] + bq.x, acc[s][1] + bq.y,
                                   acc[s][2] + bq.z, acc[s][3] + bq.w);
            *reinterpret_cast<float4*>(&z[(size_t)node * 128 + obase + og * 4]) = v;
        }
    }
}

// ------------- per-node score halves + bf16 z copy (z is L2-hot here) -------
__global__ __launch_bounds__(256) void k_scores(const float* __restrict__ z,
                                                const float* __restrict__ att,
                                                float* __restrict__ s_src,
                                                float* __restrict__ s_dst,
                                                unsigned int* __restrict__ zb, int N) {
    int gid = blockIdx.x * 256 + threadIdx.x;
    if (gid >= N * 4) return;
    int n = gid >> 2, hd = gid & 3;
    const float* zp = z + (size_t)n * 128 + hd * 32;
    const float* as = att + hd * 65;
    float ss = 0.f, sd = 0.f;
    unsigned pk[16];
#pragma unroll
    for (int i = 0; i < 32; i += 4) {
        float4 v = *reinterpret_cast<const float4*>(zp + i);
        ss += v.x * as[i] + v.y * as[i + 1] + v.z * as[i + 2] + v.w * as[i + 3];
        sd += v.x * as[32 + i] + v.y * as[32 + i + 1] + v.z * as[32 + i + 2] + v.w * as[32 + i + 3];
        pk[i / 2]     = ((unsigned)f2bf(v.y) << 16) | f2bf(v.x);
        pk[i / 2 + 1] = ((unsigned)f2bf(v.w) << 16) | f2bf(v.z);
    }
    s_src[gid] = ss;
    s_dst[gid] = sd;
    uint4* d4 = reinterpret_cast<uint4*>(zb + (size_t)n * 64 + hd * 16);
    d4[0] = make_uint4(pk[0], pk[1], pk[2], pk[3]);
    d4[1] = make_uint4(pk[4], pk[5], pk[6], pk[7]);
    d4[2] = make_uint4(pk[8], pk[9], pk[10], pk[11]);
    d4[3] = make_uint4(pk[12], pk[13], pk[14], pk[15]);
}

// ------------- CSR build: histogram -----------------------------------------
__global__ __launch_bounds__(256) void k_hist(const int* __restrict__ dst,
                                              int* __restrict__ counts, int E) {
    int e = blockIdx.x * 256 + threadIdx.x;
    if (e < E) atomicAdd(&counts[dst[e]], 1);
}

__global__ __launch_bounds__(256) void k_scan_block(const int* __restrict__ counts,
                                                    int* __restrict__ offs,
                                                    int* __restrict__ bsum, int N) {
    __shared__ int sd[256];
    int t = threadIdx.x, b = blockIdx.x;
    int i0 = b * CHUNK + t * 4;
    int c[4];
#pragma unroll
    for (int j = 0; j < 4; ++j) c[j] = (i0 + j < N) ? counts[i0 + j] : 0;
    int tsum = c[0] + c[1] + c[2] + c[3];
    sd[t] = tsum;
    __syncthreads();
    for (int d = 1; d < 256; d <<= 1) {
        int v = (t >= d) ? sd[t - d] : 0;
        __syncthreads();
        sd[t] += v;
        __syncthreads();
    }
    int pre = sd[t] - tsum;
#pragma unroll
    for (int j = 0; j < 4; ++j) {
        if (i0 + j < N) offs[i0 + j] = pre;
        pre += c[j];
    }
    if (t == 255) bsum[b] = sd[255];
}

__global__ void k_scan_top(const int* __restrict__ bsum, int* __restrict__ bscan, int nb) {
    int lane = threadIdx.x & 63;
    int x = (lane < nb) ? bsum[lane] : 0;
    int own = x;
    for (int d = 1; d < 64; d <<= 1) {
        int v = __shfl_up(x, d);
        if (lane >= d) x += v;
    }
    if (lane < nb) bscan[lane] = x - own;
}

__global__ __launch_bounds__(256) void k_addoff(int* __restrict__ offs,
                                                int* __restrict__ cursor,
                                                const int* __restrict__ bscan, int N) {
    int i = blockIdx.x * 256 + threadIdx.x;
    if (i < N) {
        int o = offs[i] + bscan[i >> 10];
        offs[i] = o;
        cursor[i] = o;
    }
}

// ------------- scatter: bucket by dst, compute alpha ONCE per edge ----------
__global__ __launch_bounds__(256) void k_scatter(const int* __restrict__ src,
                                                 const int* __restrict__ dst,
                                                 const float* __restrict__ ef,
                                                 const float* __restrict__ att,
                                                 const float* __restrict__ s_src,
                                                 const float* __restrict__ s_dst,
                                                 int* __restrict__ cursor,
                                                 int* __restrict__ s_sorted,
                                                 uint2* __restrict__ alpha2, int E) {
    int e = blockIdx.x * 256 + threadIdx.x;
    if (e >= E) return;
    int s = src[e], d = dst[e];
    float f = ef[e];
    int pos = atomicAdd(&cursor[d], 1);
    float4 ss = *reinterpret_cast<const float4*>(&s_src[(size_t)s * 4]);
    float4 sd = *reinterpret_cast<const float4*>(&s_dst[(size_t)d * 4]);
    const float* ssp = (const float*)&ss;
    const float* sdp = (const float*)&sd;
    float a[4];
#pragma unroll
    for (int hd = 0; hd < 4; ++hd) {
        float sc = ssp[hd] + sdp[hd] + f * att[hd * 65 + 64];
        sc = sc >= 0.f ? sc : 0.2f * sc;
        sc = fminf(fmaxf(sc, -20.f), 20.f);
        a[hd] = expf(sc);
    }
    s_sorted[pos] = s;
    alpha2[pos] = make_uint2(((unsigned)f2bf(a[1]) << 16) | f2bf(a[0]),
                             ((unsigned)f2bf(a[3]) << 16) | f2bf(a[2]));
}

// ------------- fused: aggregate (bf16 z) + residual + LN + ELU --------------
__global__ __launch_bounds__(256) void k_agg_final(const int* __restrict__ offs,
                                                   const int* __restrict__ counts,
                                                   const int* __restrict__ s_sorted,
                                                   const uint2* __restrict__ alpha2,
                                                   const unsigned int* __restrict__ zb,
                                                   const float* __restrict__ z,
                                                   const float* __restrict__ g,
                                                   const float* __restrict__ bparm,
                                                   float* __restrict__ out, int N) {
    int wave = threadIdx.x >> 6, lane = threadIdx.x & 63;
    int n = blockIdx.x * 4 + wave;
    if (n >= N) return;
    const int start = offs[n], len = counts[n];
    const int hd = lane >> 4;
    const int c = lane * 2;
    float ax = 0.f, ay = 0.f, da = 0.f;
    float bx = 0.f, by = 0.f, db = 0.f;
    int i = start;
    const int end = start + len;
    for (; i + 1 < end; i += 2) {
        int s0 = s_sorted[i], s1 = s_sorted[i + 1];
        uint2 al0 = alpha2[i], al1 = alpha2[i + 1];
        unsigned p0 = zb[(size_t)s0 * 64 + lane];
        unsigned p1 = zb[(size_t)s1 * 64 + lane];
        unsigned u0 = (hd & 2) ? al0.y : al0.x;
        unsigned u1 = (hd & 2) ? al1.y : al1.x;
        float a0 = __uint_as_float((hd & 1) ? (u0 & 0xffff0000u) : (u0 << 16));
        float a1 = __uint_as_float((hd & 1) ? (u1 & 0xffff0000u) : (u1 << 16));
        float x00 = __uint_as_float(p0 << 16), x01 = __uint_as_float(p0 & 0xffff0000u);
        float x10 = __uint_as_float(p1 << 16), x11 = __uint_as_float(p1 & 0xffff0000u);
        ax += x00 * a0; ay += x01 * a0; da += a0;
        bx += x10 * a1; by += x11 * a1; db += a1;
    }
    if (i < end) {
        int s0 = s_sorted[i];
        uint2 al0 = alpha2[i];
        unsigned p0 = zb[(size_t)s0 * 64 + lane];
        unsigned u0 = (hd & 2) ? al0.y : al0.x;
        float a0 = __uint_as_float((hd & 1) ? (u0 & 0xffff0000u) : (u0 << 16));
        ax += __uint_as_float(p0 << 16) * a0;
        ay += __uint_as_float(p0 & 0xffff0000u) * a0;
        da += a0;
    }

    float inv = 1.f / (da + db + 1e-6f);
    float2 zv = *reinterpret_cast<const float2*>(&z[(size_t)n * 128 + c]);
    float x0 = (ax + bx) * inv + zv.x;
    float x1 = (ay + by) * inv + zv.y;
    float s = x0 + x1;
    for (int off = 32; off; off >>= 1) s += __shfl_xor(s, off);
    float mu = s * (1.f / 128.f);
    float d0 = x0 - mu, d1 = x1 - mu;
    float q = d0 * d0 + d1 * d1;
    for (int off = 32; off; off >>= 1) q += __shfl_xor(q, off);
    float rstd = rsqrtf(q * (1.f / 128.f) + 1e-5f);
    float2 gg = *reinterpret_cast<const float2*>(&g[c]);
    float2 bb = *reinterpret_cast<const float2*>(&bparm[c]);
    float y0 = d0 * rstd * gg.x + bb.x;
    float y1 = d1 * rstd * gg.y + bb.y;
    y0 = y0 > 0.f ? y0 : expf(y0) - 1.f;
    y1 = y1 > 0.f ? y1 : expf(y1) - 1.f;
    *reinterpret_cast<float2*>(&out[(size_t)n * 128 + c]) = make_float2(y0, y1);
}

extern "C" void kernel_launch(void* const* d_in, const int* in_sizes, int n_in,
                              void* d_out, int out_size, void* d_ws, size_t ws_size,
                              hipStream_t stream) {
    const float* h   = (const float*)d_in[0];
    const int*   ei  = (const int*)d_in[1];
    const float* ef  = (const float*)d_in[2];
    const float* Ww  = (const float*)d_in[3];
    const float* Wb  = (const float*)d_in[4];
    const float* att = (const float*)d_in[5];
    const float* lng = (const float*)d_in[6];
    const float* lnb = (const float*)d_in[7];
    float* out = (float*)d_out;

    const int N = in_sizes[0] / 128;   // 50000
    const int E = in_sizes[1] / 2;     // 800000
    const int* src = ei;
    const int* dst = ei + E;
    const int nb = (N + CHUNK - 1) / CHUNK;   // 49 (<=64 required)

    char* ws = (char*)d_ws;
    float*        z        = (float*)ws;        ws += (size_t)N * 128 * 4;
    unsigned int* zb       = (unsigned int*)ws; ws += (size_t)N * 64 * 4;
    float*        s_src    = (float*)ws;        ws += (size_t)N * 4 * 4;
    float*        s_dst    = (float*)ws;        ws += (size_t)N * 4 * 4;
    int*          counts   = (int*)ws;          ws += (size_t)N * 4;
    int*          offs     = (int*)ws;          ws += (size_t)N * 4;
    int*          cursor   = (int*)ws;          ws += (size_t)N * 4;
    int*          bsum     = (int*)ws;          ws += (size_t)64 * 4;
    int*          bscan    = (int*)ws;          ws += (size_t)64 * 4;
    int*          s_sorted = (int*)ws;          ws += (size_t)E * 4;
    uint2*        alpha2   = (uint2*)ws;        ws += (size_t)E * 8;

    hipMemsetAsync(counts, 0, (size_t)N * 4, stream);

    dim3 gGemm((N + 63) / 64, 2);
    k_gemm<<<gGemm, 256, 0, stream>>>(h, Ww, Wb, z, N);
    k_hist<<<(E + 255) / 256, 256, 0, stream>>>(dst, counts, E);
    k_scores<<<(N * 4 + 255) / 256, 256, 0, stream>>>(z, att, s_src, s_dst, zb, N);
    k_scan_block<<<nb, 256, 0, stream>>>(counts, offs, bsum, N);
    k_scan_top<<<1, 64, 0, stream>>>(bsum, bscan, nb);
    k_addoff<<<(N + 255) / 256, 256, 0, stream>>>(offs, cursor, bscan, N);
    k_scatter<<<(E + 255) / 256, 256, 0, stream>>>(src, dst, ef, att, s_src, s_dst, cursor, s_sorted, alpha2, E);
    k_agg_final<<<(N + 3) / 4, 256, 0, stream>>>(offs, counts, s_sorted, alpha2, zb, z, lng, lnb, out, N);
}

// Round 6
// 164.203 us; speedup vs baseline: 2.7708x; 1.2270x over previous
//
#include <hip/hip_runtime.h>
#include <hip/hip_bf16.h>
#include <math.h>

#define CHUNK 1024

__device__ __forceinline__ unsigned short f2bf(float f) {
    unsigned u = __float_as_uint(f);
    unsigned r = ((u >> 16) & 1u) + 0x7fffu;   // RNE
    return (unsigned short)((u + r) >> 16);
}

// ---- fused: GEMM (z = h@W^T + b) + score halves + bf16 z + dst histogram ---
// gemm part: 64 nodes x 64 outs per block, 256 threads, 4x4/thread,
// swizzled k-major Wt (2-way max conflicts). Blocks >= gemmBlocks do the
// dst histogram (overlaps with gemm instead of serializing on the stream).
__global__ __launch_bounds__(256) void k_gemm_fused(
        const float* __restrict__ h, const float* __restrict__ W,
        const float* __restrict__ bias, const float* __restrict__ att,
        const int* __restrict__ dstI, int* __restrict__ counts,
        float* __restrict__ z, unsigned int* __restrict__ zb,
        float* __restrict__ s_src, float* __restrict__ s_dst,
        int N, int E, int gemmBlocks) {
    __shared__ float Wt[128 * 64];   // 32 KB, swizzled k-major
    __shared__ float hl[64][132];    // 33.8 KB, padded row-major
    const int t = threadIdx.x;
    const int bid = blockIdx.x;

    if (bid >= gemmBlocks) {         // -------- histogram part --------
        int e = (bid - gemmBlocks) * 256 + t;
        if (e < E) atomicAdd(&counts[dstI[e]], 1);
        return;
    }

    const int by = bid & 1;
    const int obase = by * 64;
    const int n0 = (bid >> 1) * 64;

    for (int i = 0; i < 8; ++i) {
        int f = i * 256 + t;
        int ol = f >> 5;            // out row 0..63
        int m = f & 31;             // k-group (k4 = 4m)
        float4 w = *reinterpret_cast<const float4*>(&W[(size_t)(obase + ol) * 128 + m * 4]);
        int swzcol = (((ol >> 2) ^ (m & 15)) << 2) | (ol & 3);
        Wt[(4 * m + 0) * 64 + swzcol] = w.x;
        Wt[(4 * m + 1) * 64 + swzcol] = w.y;
        Wt[(4 * m + 2) * 64 + swzcol] = w.z;
        Wt[(4 * m + 3) * 64 + swzcol] = w.w;
    }
    for (int i = 0; i < 8; ++i) {
        int f = i * 256 + t;
        int r = f >> 5, k4 = (f & 31) * 4;
        int hn = n0 + r; if (hn > N - 1) hn = N - 1;
        *reinterpret_cast<float4*>(&hl[r][k4]) =
            *reinterpret_cast<const float4*>(&h[(size_t)hn * 128 + k4]);
    }
    __syncthreads();

    const int og = t & 15;          // outs obase+og*4..+3
    const int wg = t >> 4;          // nodes n0+wg*4..+3
    float acc[4][4];
#pragma unroll
    for (int s = 0; s < 4; ++s)
#pragma unroll
        for (int j = 0; j < 4; ++j) acc[s][j] = 0.f;

#pragma unroll 4
    for (int k = 0; k < 128; ++k) {
        int gq = (k >> 2) & 15;
        float4 wf = *reinterpret_cast<const float4*>(&Wt[k * 64 + ((og ^ gq) << 2)]);
        float h0 = hl[wg * 4 + 0][k];
        float h1 = hl[wg * 4 + 1][k];
        float h2 = hl[wg * 4 + 2][k];
        float h3 = hl[wg * 4 + 3][k];
        acc[0][0] += h0 * wf.x; acc[0][1] += h0 * wf.y; acc[0][2] += h0 * wf.z; acc[0][3] += h0 * wf.w;
        acc[1][0] += h1 * wf.x; acc[1][1] += h1 * wf.y; acc[1][2] += h1 * wf.z; acc[1][3] += h1 * wf.w;
        acc[2][0] += h2 * wf.x; acc[2][1] += h2 * wf.y; acc[2][2] += h2 * wf.z; acc[2][3] += h2 * wf.w;
        acc[3][0] += h3 * wf.x; acc[3][1] += h3 * wf.y; acc[3][2] += h3 * wf.z; acc[3][3] += h3 * wf.w;
    }

    // epilogue: bias, z write, bf16 pack, per-head score partials + reduce
    float4 bq = *reinterpret_cast<const float4*>(&bias[obase + og * 4]);
    const int hglob = by * 2 + (og >> 3);
    const int cj = (og & 7) * 4;
    const float* ap = att + hglob * 65 + cj;
    float attS0 = ap[0], attS1 = ap[1], attS2 = ap[2], attS3 = ap[3];
    float attD0 = ap[32], attD1 = ap[33], attD2 = ap[34], attD3 = ap[35];

#pragma unroll
    for (int s = 0; s < 4; ++s) {
        int node = n0 + wg * 4 + s;
        float4 v = make_float4(acc[s][0] + bq.x, acc[s][1] + bq.y,
                               acc[s][2] + bq.z, acc[s][3] + bq.w);
        float ss = v.x * attS0 + v.y * attS1 + v.z * attS2 + v.w * attS3;
        float sd = v.x * attD0 + v.y * attD1 + v.z * attD2 + v.w * attD3;
#pragma unroll
        for (int off = 1; off < 8; off <<= 1) {
            ss += __shfl_xor(ss, off);
            sd += __shfl_xor(sd, off);
        }
        if (node < N) {
            *reinterpret_cast<float4*>(&z[(size_t)node * 128 + obase + og * 4]) = v;
            uint2 pk = make_uint2(((unsigned)f2bf(v.y) << 16) | f2bf(v.x),
                                  ((unsigned)f2bf(v.w) << 16) | f2bf(v.z));
            *reinterpret_cast<uint2*>(&zb[(size_t)node * 64 + by * 32 + og * 2]) = pk;
            if ((og & 7) == 0) {
                s_src[(size_t)node * 4 + hglob] = ss;
                s_dst[(size_t)node * 4 + hglob] = sd;
            }
        }
    }
}

// ------------- scan with 4-aligned bucket starts ----------------------------
__global__ __launch_bounds__(256) void k_scan_block(const int* __restrict__ counts,
                                                    int* __restrict__ offs,
                                                    int* __restrict__ bsum, int N) {
    __shared__ int sd[256];
    int t = threadIdx.x, b = blockIdx.x;
    int i0 = b * CHUNK + t * 4;
    int p[4];
#pragma unroll
    for (int j = 0; j < 4; ++j)
        p[j] = (i0 + j < N) ? ((counts[i0 + j] + 3) & ~3) : 0;   // pad to 4
    int tsum = p[0] + p[1] + p[2] + p[3];
    sd[t] = tsum;
    __syncthreads();
    for (int d = 1; d < 256; d <<= 1) {
        int v = (t >= d) ? sd[t - d] : 0;
        __syncthreads();
        sd[t] += v;
        __syncthreads();
    }
    int pre = sd[t] - tsum;
#pragma unroll
    for (int j = 0; j < 4; ++j) {
        if (i0 + j < N) offs[i0 + j] = pre;
        pre += p[j];
    }
    if (t == 255) bsum[b] = sd[255];
}

__global__ void k_scan_top(const int* __restrict__ bsum, int* __restrict__ bscan, int nb) {
    int lane = threadIdx.x & 63;
    int x = (lane < nb) ? bsum[lane] : 0;
    int own = x;
    for (int d = 1; d < 64; d <<= 1) {
        int v = __shfl_up(x, d);
        if (lane >= d) x += v;
    }
    if (lane < nb) bscan[lane] = x - own;
}

__global__ __launch_bounds__(256) void k_addoff(int* __restrict__ offs,
                                                int* __restrict__ cursor,
                                                const int* __restrict__ bscan, int N) {
    int i = blockIdx.x * 256 + threadIdx.x;
    if (i < N) {
        int o = offs[i] + bscan[i >> 10];
        offs[i] = o;
        cursor[i] = o;
    }
}

// ------------- scatter: bucket by dst, alpha (fp32 x4) once per edge --------
__global__ __launch_bounds__(256) void k_scatter(const int* __restrict__ src,
                                                 const int* __restrict__ dst,
                                                 const float* __restrict__ ef,
                                                 const float* __restrict__ att,
                                                 const float* __restrict__ s_src,
                                                 const float* __restrict__ s_dst,
                                                 int* __restrict__ cursor,
                                                 int* __restrict__ s_sorted,
                                                 float* __restrict__ alphaF, int E) {
    int e = blockIdx.x * 256 + threadIdx.x;
    if (e >= E) return;
    int s = src[e], d = dst[e];
    float f = ef[e];
    int pos = atomicAdd(&cursor[d], 1);
    float4 ss = *reinterpret_cast<const float4*>(&s_src[(size_t)s * 4]);
    float4 sd = *reinterpret_cast<const float4*>(&s_dst[(size_t)d * 4]);
    const float* ssp = (const float*)&ss;
    const float* sdp = (const float*)&sd;
    float a[4];
#pragma unroll
    for (int hd = 0; hd < 4; ++hd) {
        float sc = ssp[hd] + sdp[hd] + f * att[hd * 65 + 64];
        sc = sc >= 0.f ? sc : 0.2f * sc;
        sc = fminf(fmaxf(sc, -20.f), 20.f);
        a[hd] = expf(sc);
    }
    s_sorted[pos] = s;
    *reinterpret_cast<float4*>(&alphaF[(size_t)pos * 4]) =
        make_float4(a[0], a[1], a[2], a[3]);
}

// ------------- fused: aggregate (bf16 z) + residual + LN + ELU --------------
// one 64-lane wave per node; lane owns channels [2*lane, 2*lane+1];
// buckets 4-aligned -> int4 edge loads, 4 gather chains in flight.
__global__ __launch_bounds__(256) void k_agg_final(const int* __restrict__ offs,
                                                   const int* __restrict__ counts,
                                                   const int* __restrict__ s_sorted,
                                                   const float* __restrict__ alphaF,
                                                   const unsigned int* __restrict__ zb,
                                                   const float* __restrict__ z,
                                                   const float* __restrict__ g,
                                                   const float* __restrict__ bparm,
                                                   float* __restrict__ out, int N) {
    int wave = threadIdx.x >> 6, lane = threadIdx.x & 63;
    int n = blockIdx.x * 4 + wave;
    if (n >= N) return;
    const int start = offs[n], len = counts[n];
    const int hd = lane >> 4;
    const int c = lane * 2;
    const float* af = alphaF + hd;
    float ax = 0.f, ay = 0.f, da = 0.f;
    float bx = 0.f, by = 0.f, db = 0.f;
    int i = start;
    const int end = start + len;
    for (; i + 3 < end; i += 4) {
        int4 s4 = *reinterpret_cast<const int4*>(&s_sorted[i]);   // 4-aligned
        float a0 = af[(size_t)(i + 0) * 4];
        float a1 = af[(size_t)(i + 1) * 4];
        float a2 = af[(size_t)(i + 2) * 4];
        float a3 = af[(size_t)(i + 3) * 4];
        unsigned p0 = zb[(size_t)s4.x * 64 + lane];
        unsigned p1 = zb[(size_t)s4.y * 64 + lane];
        unsigned p2 = zb[(size_t)s4.z * 64 + lane];
        unsigned p3 = zb[(size_t)s4.w * 64 + lane];
        ax += __uint_as_float(p0 << 16) * a0; ay += __uint_as_float(p0 & 0xffff0000u) * a0; da += a0;
        bx += __uint_as_float(p1 << 16) * a1; by += __uint_as_float(p1 & 0xffff0000u) * a1; db += a1;
        ax += __uint_as_float(p2 << 16) * a2; ay += __uint_as_float(p2 & 0xffff0000u) * a2; da += a2;
        bx += __uint_as_float(p3 << 16) * a3; by += __uint_as_float(p3 & 0xffff0000u) * a3; db += a3;
    }
    for (; i < end; ++i) {
        int s0 = s_sorted[i];
        float a0 = af[(size_t)i * 4];
        unsigned p0 = zb[(size_t)s0 * 64 + lane];
        ax += __uint_as_float(p0 << 16) * a0;
        ay += __uint_as_float(p0 & 0xffff0000u) * a0;
        da += a0;
    }

    float inv = 1.f / (da + db + 1e-6f);
    float2 zv = *reinterpret_cast<const float2*>(&z[(size_t)n * 128 + c]);
    float x0 = (ax + bx) * inv + zv.x;
    float x1 = (ay + by) * inv + zv.y;
    float s = x0 + x1;
    for (int off = 32; off; off >>= 1) s += __shfl_xor(s, off);
    float mu = s * (1.f / 128.f);
    float d0 = x0 - mu, d1 = x1 - mu;
    float q = d0 * d0 + d1 * d1;
    for (int off = 32; off; off >>= 1) q += __shfl_xor(q, off);
    float rstd = rsqrtf(q * (1.f / 128.f) + 1e-5f);
    float2 gg = *reinterpret_cast<const float2*>(&g[c]);
    float2 bb = *reinterpret_cast<const float2*>(&bparm[c]);
    float y0 = d0 * rstd * gg.x + bb.x;
    float y1 = d1 * rstd * gg.y + bb.y;
    y0 = y0 > 0.f ? y0 : expf(y0) - 1.f;
    y1 = y1 > 0.f ? y1 : expf(y1) - 1.f;
    *reinterpret_cast<float2*>(&out[(size_t)n * 128 + c]) = make_float2(y0, y1);
}

extern "C" void kernel_launch(void* const* d_in, const int* in_sizes, int n_in,
                              void* d_out, int out_size, void* d_ws, size_t ws_size,
                              hipStream_t stream) {
    const float* h   = (const float*)d_in[0];
    const int*   ei  = (const int*)d_in[1];
    const float* ef  = (const float*)d_in[2];
    const float* Ww  = (const float*)d_in[3];
    const float* Wb  = (const float*)d_in[4];
    const float* att = (const float*)d_in[5];
    const float* lng = (const float*)d_in[6];
    const float* lnb = (const float*)d_in[7];
    float* out = (float*)d_out;

    const int N = in_sizes[0] / 128;   // 50000
    const int E = in_sizes[1] / 2;     // 800000
    const int* src = ei;
    const int* dst = ei + E;
    const int nb = (N + CHUNK - 1) / CHUNK;       // 49 (<=64 required)
    const int sortedCap = E + 3 * N + 64;         // padded-CSR capacity

    char* ws = (char*)d_ws;
    float*        z        = (float*)ws;        ws += (size_t)N * 128 * 4;
    unsigned int* zb       = (unsigned int*)ws; ws += (size_t)N * 64 * 4;
    float*        s_src    = (float*)ws;        ws += (size_t)N * 4 * 4;
    float*        s_dst    = (float*)ws;        ws += (size_t)N * 4 * 4;
    int*          counts   = (int*)ws;          ws += (size_t)N * 4;
    int*          offs     = (int*)ws;          ws += (size_t)N * 4;
    int*          cursor   = (int*)ws;          ws += (size_t)N * 4;
    int*          bsum     = (int*)ws;          ws += (size_t)64 * 4;
    int*          bscan    = (int*)ws;          ws += (size_t)64 * 4;
    int*          s_sorted = (int*)ws;          ws += (size_t)sortedCap * 4;
    float*        alphaF   = (float*)ws;        ws += (size_t)sortedCap * 16;

    hipMemsetAsync(counts, 0, (size_t)N * 4, stream);

    const int gemmBlocks = ((N + 63) / 64) * 2;
    const int histBlocks = (E + 255) / 256;
    k_gemm_fused<<<gemmBlocks + histBlocks, 256, 0, stream>>>(
        h, Ww, Wb, att, dst, counts, z, zb, s_src, s_dst, N, E, gemmBlocks);
    k_scan_block<<<nb, 256, 0, stream>>>(counts, offs, bsum, N);
    k_scan_top<<<1, 64, 0, stream>>>(bsum, bscan, nb);
    k_addoff<<<(N + 255) / 256, 256, 0, stream>>>(offs, cursor, bscan, N);
    k_scatter<<<(E + 255) / 256, 256, 0, stream>>>(src, dst, ef, att, s_src, s_dst, cursor, s_sorted, alphaF, E);
    k_agg_final<<<(N + 3) / 4, 256, 0, stream>>>(offs, counts, s_sorted, alphaF, zb, z, lng, lnb, out, N);
}